// Round 12
// baseline (212.440 us; speedup 1.0000x reference)
//
#include <hip/hip_runtime.h>
#include <hip/hip_fp16.h>
#include <math.h>

// GCN 2-layer: N=100000 nodes, E=3200000 edges, 128 -> 16 -> 7
// R22: R21 base (211.2us best) + 3-stage agg pipeline: iteration k issues
//      batch k+1's GATHERS and batch k+2's index loads before batch k's math
//      -> gather latency (~200-300cy L2) gets a full iteration of cover
//      (R21's 2-stage only covered the index loads; gathers had ~80cy).
//      Cost: +~24 VGPR (e/f/u triple-buffer), occupancy 6->~5 waves/SIMD;
//      R14 lesson: per-lane MLP outweighs modest occupancy loss.
constexpr int NN = 100000;
constexpr int NE = 3200000;
constexpr int DF = 128;
constexpr int NH = 16;
constexpr int NC = 7;

constexpr int BN    = 256;                      // nodes per dst bucket (pow2)
constexpr int NB    = (NN + BN - 1) / BN;       // 391 buckets
constexpr int CAP   = 9216;                     // slots per bucket (mean 8184 + ~11 sigma)
constexpr int CHUNK = 4096;                     // edges per append block
constexpr int AB    = (NE + CHUNK - 1) / CHUNK; // 782
constexpr int EPT   = CHUNK / 1024;             // 4 edges per thread
constexpr int SPT   = (CAP + 1023) / 1024;      // 9 stash slots in sort

constexpr float QS   = 32767.0f;
constexpr float QINV = 1.0f / 32767.0f;

typedef _Float16 half8 __attribute__((ext_vector_type(8)));
typedef float    f32x4 __attribute__((ext_vector_type(4)));

// ---------------- bucket append: LDS chunk-local counting sort, coalesced flush ----------------
__global__ void __launch_bounds__(1024)
k_append(const int* __restrict__ src,
         const int* __restrict__ dst,
         const float* __restrict__ w,
         int* __restrict__ gcur,
         uint2* __restrict__ ebuf) {
    __shared__ int hist[NB];                 // per-bucket count in this chunk
    __shared__ int cscan[512];               // inclusive scan of hist (padded)
    __shared__ int basev[NB];                // global base for this chunk's run
    __shared__ int wsum[8];                  // wave partials for scan
    __shared__ uint2 staged[CHUNK];          // 32 KB: chunk edges grouped by bucket
    int tid = threadIdx.x;
    for (int i = tid; i < NB; i += 1024) hist[i] = 0;
    __syncthreads();
    int e0 = blockIdx.x * CHUNK;
    unsigned slo[EPT], sw[EPT];
    int sbr[EPT];
#pragma unroll
    for (int k = 0; k < EPT; ++k) {
        int e = e0 + tid + k * 1024;
        sbr[k] = -1;
        if (e < NE) {
            int d = __builtin_nontemporal_load(dst + e);
            int b = d >> 8;
            int r = atomicAdd(&hist[b], 1);             // the only per-edge atomic
            slo[k] = ((unsigned)(d & (BN - 1)) << 17) |
                     (unsigned)__builtin_nontemporal_load(src + e);
            unsigned q = (unsigned)(__builtin_nontemporal_load(w + e) * QS + 0.5f);
            sw[k]  = ((unsigned)b << 15) | q;           // b (9b) | q (15b)
            sbr[k] = (b << 13) | r;                     // b<391 (9b), r<4096 (13b)
        }
    }
    __syncthreads();
    // inclusive scan of hist over 512 entries: 8 fully-active waves, shfl_up
    {
        int v = 0;
        if (tid < 512) {
            v = (tid < NB) ? hist[tid] : 0;
#pragma unroll
            for (int d = 1; d < 64; d <<= 1) {
                int u = __shfl_up(v, d, 64);
                if ((tid & 63) >= d) v += u;
            }
            if ((tid & 63) == 63) wsum[tid >> 6] = v;
        }
        __syncthreads();
        if (tid == 0) {
            int acc = 0;
#pragma unroll
            for (int i = 0; i < 8; ++i) { int t = wsum[i]; wsum[i] = acc; acc += t; }
        }
        __syncthreads();
        if (tid < 512) cscan[tid] = v + wsum[tid >> 6];
    }
    __syncthreads();
    if (tid < NB) {
        int c = hist[tid];
        basev[tid] = (c > 0) ? atomicAdd(&gcur[tid], c) : 0;
    }
    __syncthreads();
    // stage: LDS scatter into bucket-grouped order
#pragma unroll
    for (int k = 0; k < EPT; ++k) {
        if (sbr[k] >= 0) {
            int b = sbr[k] >> 13;
            int idx = (cscan[b] - hist[b]) + (sbr[k] & 0x1FFF);
            uint2 v; v.x = slo[k]; v.y = sw[k];
            staged[idx] = v;
        }
    }
    __syncthreads();
    // flush: consecutive lanes write consecutive global slots within each bucket run
    int total = min(CHUNK, NE - e0);
    for (int i = tid; i < total; i += 1024) {
        uint2 sv = staged[i];
        int b = (int)(sv.y >> 15);
        int st = cscan[b] - hist[b];
        int pos = basev[b] + (i - st);
        if (pos < CAP) ebuf[(size_t)b * CAP + pos] = sv;
    }
}

// ---------------- intra-bucket counting sort: single LDS atomic/edge ----------------
__global__ void __launch_bounds__(1024)
k_sort(const int* __restrict__ gcur,
       uint2* __restrict__ ebuf,
       int* __restrict__ rs,
       int* __restrict__ rc,
       float* __restrict__ dinv) {
    __shared__ int cursor[BN];    // counts after loop1
    __shared__ int scanS[BN];
    __shared__ int startEx[BN];
    __shared__ int wsum[4];
    __shared__ unsigned sorted[CAP];  // 36 KB
    int b = blockIdx.x;
    int tid = threadIdx.x;
    int cnt = min(gcur[b], CAP);
    const uint2* eb = ebuf + (size_t)b * CAP;
    if (tid < BN) cursor[tid] = 0;
    __syncthreads();
    unsigned sval[SPT];
    int sdr[SPT];
#pragma unroll
    for (int k = 0; k < SPT; ++k) {
        int i = tid + k * 1024;
        sdr[k] = -1;
        if (i < cnt) {
            uint2 v = eb[i];
            int dl = (v.x >> 17) & (BN - 1);
            int r = atomicAdd(&cursor[dl], 1);          // the only per-edge atomic
            sval[k] = (v.x & 0x1FFFF) | ((v.y & 0x7FFFu) << 17);  // src | q
            sdr[k] = (dl << 14) | r;                    // dl (8b), r<9216 (14b)
        }
    }
    __syncthreads();
    // inclusive scan of cursor over 256 entries: 4 fully-active waves, shfl_up
    {
        int v = 0;
        if (tid < BN) {
            v = cursor[tid];
#pragma unroll
            for (int d = 1; d < 64; d <<= 1) {
                int u = __shfl_up(v, d, 64);
                if ((tid & 63) >= d) v += u;
            }
            if ((tid & 63) == 63) wsum[tid >> 6] = v;
        }
        __syncthreads();
        if (tid == 0) {
            int acc = 0;
#pragma unroll
            for (int i = 0; i < 4; ++i) { int t = wsum[i]; wsum[i] = acc; acc += t; }
        }
        __syncthreads();
        if (tid < BN) scanS[tid] = v + wsum[tid >> 6];
    }
    __syncthreads();
    if (tid < BN) {
        int ex = scanS[tid] - cursor[tid];
        startEx[tid] = ex;
        int n = b * BN + tid;
        if (n < NN) { rs[n] = b * CAP * 2 + ex; rc[n] = cursor[tid]; }  // u32 index
    }
    __syncthreads();
#pragma unroll
    for (int k = 0; k < SPT; ++k) {
        if (sdr[k] >= 0)
            sorted[startEx[sdr[k] >> 14] + (sdr[k] & 0x3FFF)] = sval[k];
    }
    __syncthreads();
    unsigned* eb32 = (unsigned*)ebuf + (size_t)b * CAP * 2;
    for (int i = tid; i < cnt; i += 1024) eb32[i] = sorted[i];
    // dinv: 4 threads per node, shfl-reduce
    {
        int node = tid >> 2, part = tid & 3;
        float s = (part == 0) ? 1.0f : 0.0f;  // self-loop
        int s0 = startEx[node], c = cursor[node];
        for (int i = part; i < c; i += 4) s += (float)(sorted[s0 + i] >> 17) * QINV;
        s += __shfl_xor(s, 1, 4);
        s += __shfl_xor(s, 2, 4);
        if (part == 0) {
            int n = b * BN + node;
            if (n < NN) dinv[n] = rsqrtf(s);
        }
    }
}

// ---------------- h1' = fp16( dinv * (x @ W1) ) via MFMA, 1 wave per 16 nodes ----------------
__global__ void __launch_bounds__(256)
k_proj1(const float* __restrict__ x,
        const float* __restrict__ W1,
        const float* __restrict__ dinv,
        __half* __restrict__ h1p) {
    int wave = threadIdx.x >> 6;
    int lane = threadIdx.x & 63;
    int tile = blockIdx.x * 4 + wave;
    if (tile * 16 >= NN) return;
    int m    = lane & 15;   // A row (node within tile); also B/C column (feature)
    int quad = lane >> 4;
    // B fragments: B[k][n] with n = lane&15, k = kc*32 + quad*8 + j
    half8 bfrag[4];
#pragma unroll
    for (int kc = 0; kc < 4; ++kc)
#pragma unroll
        for (int j = 0; j < 8; ++j)
            bfrag[kc][j] = (_Float16)W1[(kc * 32 + quad * 8 + j) * NH + m];
    int base = tile * 16;
    const float* xr = x + (size_t)(base + m) * DF + quad * 8;
    f32x4 acc = {0.f, 0.f, 0.f, 0.f};
#pragma unroll
    for (int kc = 0; kc < 4; ++kc) {
        const float4* p = (const float4*)(xr + kc * 32);
        float4 u0 = p[0];
        float4 u1 = p[1];
        half8 afrag;
        afrag[0] = (_Float16)u0.x; afrag[1] = (_Float16)u0.y;
        afrag[2] = (_Float16)u0.z; afrag[3] = (_Float16)u0.w;
        afrag[4] = (_Float16)u1.x; afrag[5] = (_Float16)u1.y;
        afrag[6] = (_Float16)u1.z; afrag[7] = (_Float16)u1.w;
        acc = __builtin_amdgcn_mfma_f32_16x16x32_f16(afrag, bfrag[kc], acc, 0, 0, 0);
    }
    // epilogue: D[row=quad*4+reg][col=m] * dinv[row] -> h1p[(base+row)*16 + m]
    float4 d4 = *(const float4*)(dinv + base + quad * 4);
#pragma unroll
    for (int reg = 0; reg < 4; ++reg) {
        float dd = (reg == 0) ? d4.x : (reg == 1) ? d4.y : (reg == 2) ? d4.z : d4.w;
        int row = quad * 4 + reg;
        h1p[(size_t)(base + row) * 16 + m] = __float2half(acc[reg] * dd);
    }
}

// ---------------- layer-1 aggregate + relu + proj2 fused (4 lanes/node, 3-stage pipeline) ----------------
__global__ void __launch_bounds__(256)
k_agg1p(const int* __restrict__ rs,
        const int* __restrict__ rc,
        const unsigned* __restrict__ cbuf,
        const __half* __restrict__ h1p,
        const float* __restrict__ dinv,
        const float* __restrict__ b1,
        const float* __restrict__ W2,
        __half* __restrict__ h2p) {
    const uint2* hp4 = (const uint2*)h1p;  // [NN*4], 4 halves each
    int t = blockIdx.x * 256 + threadIdx.x;
    int n = t >> 2;
    int f4 = t & 3;   // features 4*f4 .. 4*f4+3
    if (n >= NN) return;
    float a0, a1, a2, a3;
    {
        uint2 u = hp4[n * 4 + f4];  // self term
        float2 lo = __half22float2(*(const __half2*)&u.x);
        float2 hi = __half22float2(*(const __half2*)&u.y);
        a0 = lo.x; a1 = lo.y; a2 = hi.x; a3 = hi.y;
    }
    int s0 = rs[n], c = rc[n];
    int i = 0;
    if (c >= 16) {
        // prologue: batch0 indices + gathers, batch1 indices
        unsigned e0 = cbuf[s0 + 0], e1 = cbuf[s0 + 1], e2 = cbuf[s0 + 2], e3 = cbuf[s0 + 3];
        unsigned e4 = cbuf[s0 + 4], e5 = cbuf[s0 + 5], e6 = cbuf[s0 + 6], e7 = cbuf[s0 + 7];
        unsigned f0 = cbuf[s0 + 8], f1 = cbuf[s0 + 9], f2 = cbuf[s0 + 10], f3 = cbuf[s0 + 11];
        unsigned f4r = cbuf[s0 + 12], f5 = cbuf[s0 + 13], f6 = cbuf[s0 + 14], f7 = cbuf[s0 + 15];
        uint2 u0 = hp4[(e0 & 0x1FFFF) * 4 + f4];
        uint2 u1 = hp4[(e1 & 0x1FFFF) * 4 + f4];
        uint2 u2 = hp4[(e2 & 0x1FFFF) * 4 + f4];
        uint2 u3 = hp4[(e3 & 0x1FFFF) * 4 + f4];
        uint2 u4 = hp4[(e4 & 0x1FFFF) * 4 + f4];
        uint2 u5 = hp4[(e5 & 0x1FFFF) * 4 + f4];
        uint2 u6 = hp4[(e6 & 0x1FFFF) * 4 + f4];
        uint2 u7 = hp4[(e7 & 0x1FFFF) * 4 + f4];
        for (; i + 23 < c; i += 8) {
            // issue batch k+1's gathers (indices f already resident)
            uint2 v0 = hp4[(f0 & 0x1FFFF) * 4 + f4];
            uint2 v1 = hp4[(f1 & 0x1FFFF) * 4 + f4];
            uint2 v2 = hp4[(f2 & 0x1FFFF) * 4 + f4];
            uint2 v3 = hp4[(f3 & 0x1FFFF) * 4 + f4];
            uint2 v4 = hp4[(f4r & 0x1FFFF) * 4 + f4];
            uint2 v5 = hp4[(f5 & 0x1FFFF) * 4 + f4];
            uint2 v6 = hp4[(f6 & 0x1FFFF) * 4 + f4];
            uint2 v7 = hp4[(f7 & 0x1FFFF) * 4 + f4];
            // load batch k+2's indices
            unsigned g0 = cbuf[s0 + i + 16], g1 = cbuf[s0 + i + 17];
            unsigned g2 = cbuf[s0 + i + 18], g3 = cbuf[s0 + i + 19];
            unsigned g4 = cbuf[s0 + i + 20], g5 = cbuf[s0 + i + 21];
            unsigned g6 = cbuf[s0 + i + 22], g7 = cbuf[s0 + i + 23];
            // math on batch k (u gathered a full iteration ago)
            float w0 = (float)(e0 >> 17) * QINV;
            float w1 = (float)(e1 >> 17) * QINV;
            float w2 = (float)(e2 >> 17) * QINV;
            float w3 = (float)(e3 >> 17) * QINV;
            float w4 = (float)(e4 >> 17) * QINV;
            float w5 = (float)(e5 >> 17) * QINV;
            float w6 = (float)(e6 >> 17) * QINV;
            float w7 = (float)(e7 >> 17) * QINV;
            float2 l0 = __half22float2(*(const __half2*)&u0.x);
            float2 h0 = __half22float2(*(const __half2*)&u0.y);
            float2 l1 = __half22float2(*(const __half2*)&u1.x);
            float2 h1v = __half22float2(*(const __half2*)&u1.y);
            float2 l2 = __half22float2(*(const __half2*)&u2.x);
            float2 h2v = __half22float2(*(const __half2*)&u2.y);
            float2 l3 = __half22float2(*(const __half2*)&u3.x);
            float2 h3v = __half22float2(*(const __half2*)&u3.y);
            float2 l4 = __half22float2(*(const __half2*)&u4.x);
            float2 h4v = __half22float2(*(const __half2*)&u4.y);
            float2 l5 = __half22float2(*(const __half2*)&u5.x);
            float2 h5v = __half22float2(*(const __half2*)&u5.y);
            float2 l6 = __half22float2(*(const __half2*)&u6.x);
            float2 h6v = __half22float2(*(const __half2*)&u6.y);
            float2 l7 = __half22float2(*(const __half2*)&u7.x);
            float2 h7v = __half22float2(*(const __half2*)&u7.y);
            a0 += w0 * l0.x + w1 * l1.x + w2 * l2.x + w3 * l3.x
                + w4 * l4.x + w5 * l5.x + w6 * l6.x + w7 * l7.x;
            a1 += w0 * l0.y + w1 * l1.y + w2 * l2.y + w3 * l3.y
                + w4 * l4.y + w5 * l5.y + w6 * l6.y + w7 * l7.y;
            a2 += w0 * h0.x + w1 * h1v.x + w2 * h2v.x + w3 * h3v.x
                + w4 * h4v.x + w5 * h5v.x + w6 * h6v.x + w7 * h7v.x;
            a3 += w0 * h0.y + w1 * h1v.y + w2 * h2v.y + w3 * h3v.y
                + w4 * h4v.y + w5 * h5v.y + w6 * h6v.y + w7 * h7v.y;
            // rotate pipeline registers
            e0 = f0; e1 = f1; e2 = f2; e3 = f3; e4 = f4r; e5 = f5; e6 = f6; e7 = f7;
            f0 = g0; f1 = g1; f2 = g2; f3 = g3; f4r = g4; f5 = g5; f6 = g6; f7 = g7;
            u0 = v0; u1 = v1; u2 = v2; u3 = v3; u4 = v4; u5 = v5; u6 = v6; u7 = v7;
        }
        // epilogue A: gathers for batch f, math on batch e/u
        {
            uint2 v0 = hp4[(f0 & 0x1FFFF) * 4 + f4];
            uint2 v1 = hp4[(f1 & 0x1FFFF) * 4 + f4];
            uint2 v2 = hp4[(f2 & 0x1FFFF) * 4 + f4];
            uint2 v3 = hp4[(f3 & 0x1FFFF) * 4 + f4];
            uint2 v4 = hp4[(f4r & 0x1FFFF) * 4 + f4];
            uint2 v5 = hp4[(f5 & 0x1FFFF) * 4 + f4];
            uint2 v6 = hp4[(f6 & 0x1FFFF) * 4 + f4];
            uint2 v7 = hp4[(f7 & 0x1FFFF) * 4 + f4];
            float w0 = (float)(e0 >> 17) * QINV;
            float w1 = (float)(e1 >> 17) * QINV;
            float w2 = (float)(e2 >> 17) * QINV;
            float w3 = (float)(e3 >> 17) * QINV;
            float w4 = (float)(e4 >> 17) * QINV;
            float w5 = (float)(e5 >> 17) * QINV;
            float w6 = (float)(e6 >> 17) * QINV;
            float w7 = (float)(e7 >> 17) * QINV;
            float2 l0 = __half22float2(*(const __half2*)&u0.x);
            float2 h0 = __half22float2(*(const __half2*)&u0.y);
            float2 l1 = __half22float2(*(const __half2*)&u1.x);
            float2 h1v = __half22float2(*(const __half2*)&u1.y);
            float2 l2 = __half22float2(*(const __half2*)&u2.x);
            float2 h2v = __half22float2(*(const __half2*)&u2.y);
            float2 l3 = __half22float2(*(const __half2*)&u3.x);
            float2 h3v = __half22float2(*(const __half2*)&u3.y);
            float2 l4 = __half22float2(*(const __half2*)&u4.x);
            float2 h4v = __half22float2(*(const __half2*)&u4.y);
            float2 l5 = __half22float2(*(const __half2*)&u5.x);
            float2 h5v = __half22float2(*(const __half2*)&u5.y);
            float2 l6 = __half22float2(*(const __half2*)&u6.x);
            float2 h6v = __half22float2(*(const __half2*)&u6.y);
            float2 l7 = __half22float2(*(const __half2*)&u7.x);
            float2 h7v = __half22float2(*(const __half2*)&u7.y);
            a0 += w0 * l0.x + w1 * l1.x + w2 * l2.x + w3 * l3.x
                + w4 * l4.x + w5 * l5.x + w6 * l6.x + w7 * l7.x;
            a1 += w0 * l0.y + w1 * l1.y + w2 * l2.y + w3 * l3.y
                + w4 * l4.y + w5 * l5.y + w6 * l6.y + w7 * l7.y;
            a2 += w0 * h0.x + w1 * h1v.x + w2 * h2v.x + w3 * h3v.x
                + w4 * h4v.x + w5 * h5v.x + w6 * h6v.x + w7 * h7v.x;
            a3 += w0 * h0.y + w1 * h1v.y + w2 * h2v.y + w3 * h3v.y
                + w4 * h4v.y + w5 * h5v.y + w6 * h6v.y + w7 * h7v.y;
            e0 = f0; e1 = f1; e2 = f2; e3 = f3; e4 = f4r; e5 = f5; e6 = f6; e7 = f7;
            u0 = v0; u1 = v1; u2 = v2; u3 = v3; u4 = v4; u5 = v5; u6 = v6; u7 = v7;
            i += 8;
        }
        // epilogue B: math on final batch
        {
            float w0 = (float)(e0 >> 17) * QINV;
            float w1 = (float)(e1 >> 17) * QINV;
            float w2 = (float)(e2 >> 17) * QINV;
            float w3 = (float)(e3 >> 17) * QINV;
            float w4 = (float)(e4 >> 17) * QINV;
            float w5 = (float)(e5 >> 17) * QINV;
            float w6 = (float)(e6 >> 17) * QINV;
            float w7 = (float)(e7 >> 17) * QINV;
            float2 l0 = __half22float2(*(const __half2*)&u0.x);
            float2 h0 = __half22float2(*(const __half2*)&u0.y);
            float2 l1 = __half22float2(*(const __half2*)&u1.x);
            float2 h1v = __half22float2(*(const __half2*)&u1.y);
            float2 l2 = __half22float2(*(const __half2*)&u2.x);
            float2 h2v = __half22float2(*(const __half2*)&u2.y);
            float2 l3 = __half22float2(*(const __half2*)&u3.x);
            float2 h3v = __half22float2(*(const __half2*)&u3.y);
            float2 l4 = __half22float2(*(const __half2*)&u4.x);
            float2 h4v = __half22float2(*(const __half2*)&u4.y);
            float2 l5 = __half22float2(*(const __half2*)&u5.x);
            float2 h5v = __half22float2(*(const __half2*)&u5.y);
            float2 l6 = __half22float2(*(const __half2*)&u6.x);
            float2 h6v = __half22float2(*(const __half2*)&u6.y);
            float2 l7 = __half22float2(*(const __half2*)&u7.x);
            float2 h7v = __half22float2(*(const __half2*)&u7.y);
            a0 += w0 * l0.x + w1 * l1.x + w2 * l2.x + w3 * l3.x
                + w4 * l4.x + w5 * l5.x + w6 * l6.x + w7 * l7.x;
            a1 += w0 * l0.y + w1 * l1.y + w2 * l2.y + w3 * l3.y
                + w4 * l4.y + w5 * l5.y + w6 * l6.y + w7 * l7.y;
            a2 += w0 * h0.x + w1 * h1v.x + w2 * h2v.x + w3 * h3v.x
                + w4 * h4v.x + w5 * h5v.x + w6 * h6v.x + w7 * h7v.x;
            a3 += w0 * h0.y + w1 * h1v.y + w2 * h2v.y + w3 * h3v.y
                + w4 * h4v.y + w5 * h5v.y + w6 * h6v.y + w7 * h7v.y;
            i += 8;
        }
    }
    for (; i + 3 < c; i += 4) {
        unsigned e0 = cbuf[s0 + i];
        unsigned e1 = cbuf[s0 + i + 1];
        unsigned e2 = cbuf[s0 + i + 2];
        unsigned e3 = cbuf[s0 + i + 3];
        uint2 u0 = hp4[(e0 & 0x1FFFF) * 4 + f4];
        uint2 u1 = hp4[(e1 & 0x1FFFF) * 4 + f4];
        uint2 u2 = hp4[(e2 & 0x1FFFF) * 4 + f4];
        uint2 u3 = hp4[(e3 & 0x1FFFF) * 4 + f4];
        float w0 = (float)(e0 >> 17) * QINV;
        float w1 = (float)(e1 >> 17) * QINV;
        float w2 = (float)(e2 >> 17) * QINV;
        float w3 = (float)(e3 >> 17) * QINV;
        float2 l0 = __half22float2(*(const __half2*)&u0.x);
        float2 h0 = __half22float2(*(const __half2*)&u0.y);
        float2 l1 = __half22float2(*(const __half2*)&u1.x);
        float2 h1v = __half22float2(*(const __half2*)&u1.y);
        float2 l2 = __half22float2(*(const __half2*)&u2.x);
        float2 h2v = __half22float2(*(const __half2*)&u2.y);
        float2 l3 = __half22float2(*(const __half2*)&u3.x);
        float2 h3v = __half22float2(*(const __half2*)&u3.y);
        a0 += w0 * l0.x + w1 * l1.x + w2 * l2.x + w3 * l3.x;
        a1 += w0 * l0.y + w1 * l1.y + w2 * l2.y + w3 * l3.y;
        a2 += w0 * h0.x + w1 * h1v.x + w2 * h2v.x + w3 * h3v.x;
        a3 += w0 * h0.y + w1 * h1v.y + w2 * h2v.y + w3 * h3v.y;
    }
    for (; i < c; ++i) {
        unsigned e0 = cbuf[s0 + i];
        uint2 u0 = hp4[(e0 & 0x1FFFF) * 4 + f4];
        float w0 = (float)(e0 >> 17) * QINV;
        float2 l0 = __half22float2(*(const __half2*)&u0.x);
        float2 h0 = __half22float2(*(const __half2*)&u0.y);
        a0 += w0 * l0.x;
        a1 += w0 * l0.y;
        a2 += w0 * h0.x;
        a3 += w0 * h0.y;
    }
    // fused epilogue: out1 = di*a + b1, relu, @W2, *di -> h2p (fp16)
    float di = dinv[n];
    int fb = 4 * f4;
    float hr0 = fmaxf(di * a0 + b1[fb + 0], 0.0f);
    float hr1 = fmaxf(di * a1 + b1[fb + 1], 0.0f);
    float hr2 = fmaxf(di * a2 + b1[fb + 2], 0.0f);
    float hr3 = fmaxf(di * a3 + b1[fb + 3], 0.0f);
    float p0, p1, p2, p3, p4, p5, p6;
    {
        const float* w0r = W2 + (fb + 0) * NC;
        const float* w1r = W2 + (fb + 1) * NC;
        const float* w2r = W2 + (fb + 2) * NC;
        const float* w3r = W2 + (fb + 3) * NC;
        p0 = hr0 * w0r[0] + hr1 * w1r[0] + hr2 * w2r[0] + hr3 * w3r[0];
        p1 = hr0 * w0r[1] + hr1 * w1r[1] + hr2 * w2r[1] + hr3 * w3r[1];
        p2 = hr0 * w0r[2] + hr1 * w1r[2] + hr2 * w2r[2] + hr3 * w3r[2];
        p3 = hr0 * w0r[3] + hr1 * w1r[3] + hr2 * w2r[3] + hr3 * w3r[3];
        p4 = hr0 * w0r[4] + hr1 * w1r[4] + hr2 * w2r[4] + hr3 * w3r[4];
        p5 = hr0 * w0r[5] + hr1 * w1r[5] + hr2 * w2r[5] + hr3 * w3r[5];
        p6 = hr0 * w0r[6] + hr1 * w1r[6] + hr2 * w2r[6] + hr3 * w3r[6];
    }
#pragma unroll
    for (int mask = 1; mask < 4; mask <<= 1) {
        p0 += __shfl_xor(p0, mask, 4);
        p1 += __shfl_xor(p1, mask, 4);
        p2 += __shfl_xor(p2, mask, 4);
        p3 += __shfl_xor(p3, mask, 4);
        p4 += __shfl_xor(p4, mask, 4);
        p5 += __shfl_xor(p5, mask, 4);
        p6 += __shfl_xor(p6, mask, 4);
    }
    // lane f4 writes classes 2*f4, 2*f4+1 (lane 3 second = pad 0)
    float pa = (f4 == 0) ? p0 : (f4 == 1) ? p2 : (f4 == 2) ? p4 : p6;
    float pb = (f4 == 0) ? p1 : (f4 == 1) ? p3 : (f4 == 2) ? p5 : 0.0f;
    __half2 hv;
    hv.x = __float2half(di * pa);
    hv.y = __float2half(di * pb);
    ((__half2*)h2p)[n * 4 + f4] = hv;
}

// ---------------- layer-2 aggregate (2 lanes/node, 3-stage pipeline) + bias + log_softmax ----------------
__global__ void __launch_bounds__(256)
k_agg2_lsm(const int* __restrict__ rs,
           const int* __restrict__ rc,
           const unsigned* __restrict__ cbuf,
           const __half* __restrict__ h2p,
           const float* __restrict__ dinv,
           const float* __restrict__ b2,
           float* __restrict__ out) {
    const uint2* hp2 = (const uint2*)h2p;  // [NN*2], 4 halves each
    int t = blockIdx.x * 256 + threadIdx.x;
    int n = t >> 1;
    int c2 = t & 1;   // classes 4*c2 .. 4*c2+3 (lane1 last = pad)
    if (n >= NN) return;
    float a0, a1, a2, a3;
    {
        uint2 u = hp2[n * 2 + c2];  // self term (pad slot = 0)
        float2 lo = __half22float2(*(const __half2*)&u.x);
        float2 hi = __half22float2(*(const __half2*)&u.y);
        a0 = lo.x; a1 = lo.y; a2 = hi.x; a3 = hi.y;
    }
    int s0 = rs[n], c = rc[n];
    int i = 0;
    if (c >= 16) {
        unsigned e0 = cbuf[s0 + 0], e1 = cbuf[s0 + 1], e2 = cbuf[s0 + 2], e3 = cbuf[s0 + 3];
        unsigned e4 = cbuf[s0 + 4], e5 = cbuf[s0 + 5], e6 = cbuf[s0 + 6], e7 = cbuf[s0 + 7];
        unsigned f0 = cbuf[s0 + 8], f1 = cbuf[s0 + 9], f2 = cbuf[s0 + 10], f3 = cbuf[s0 + 11];
        unsigned f4r = cbuf[s0 + 12], f5 = cbuf[s0 + 13], f6 = cbuf[s0 + 14], f7 = cbuf[s0 + 15];
        uint2 u0 = hp2[(e0 & 0x1FFFF) * 2 + c2];
        uint2 u1 = hp2[(e1 & 0x1FFFF) * 2 + c2];
        uint2 u2 = hp2[(e2 & 0x1FFFF) * 2 + c2];
        uint2 u3 = hp2[(e3 & 0x1FFFF) * 2 + c2];
        uint2 u4 = hp2[(e4 & 0x1FFFF) * 2 + c2];
        uint2 u5 = hp2[(e5 & 0x1FFFF) * 2 + c2];
        uint2 u6 = hp2[(e6 & 0x1FFFF) * 2 + c2];
        uint2 u7 = hp2[(e7 & 0x1FFFF) * 2 + c2];
        for (; i + 23 < c; i += 8) {
            uint2 v0 = hp2[(f0 & 0x1FFFF) * 2 + c2];
            uint2 v1 = hp2[(f1 & 0x1FFFF) * 2 + c2];
            uint2 v2 = hp2[(f2 & 0x1FFFF) * 2 + c2];
            uint2 v3 = hp2[(f3 & 0x1FFFF) * 2 + c2];
            uint2 v4 = hp2[(f4r & 0x1FFFF) * 2 + c2];
            uint2 v5 = hp2[(f5 & 0x1FFFF) * 2 + c2];
            uint2 v6 = hp2[(f6 & 0x1FFFF) * 2 + c2];
            uint2 v7 = hp2[(f7 & 0x1FFFF) * 2 + c2];
            unsigned g0 = cbuf[s0 + i + 16], g1 = cbuf[s0 + i + 17];
            unsigned g2 = cbuf[s0 + i + 18], g3 = cbuf[s0 + i + 19];
            unsigned g4 = cbuf[s0 + i + 20], g5 = cbuf[s0 + i + 21];
            unsigned g6 = cbuf[s0 + i + 22], g7 = cbuf[s0 + i + 23];
            float w0 = (float)(e0 >> 17) * QINV;
            float w1 = (float)(e1 >> 17) * QINV;
            float w2 = (float)(e2 >> 17) * QINV;
            float w3 = (float)(e3 >> 17) * QINV;
            float w4 = (float)(e4 >> 17) * QINV;
            float w5 = (float)(e5 >> 17) * QINV;
            float w6 = (float)(e6 >> 17) * QINV;
            float w7 = (float)(e7 >> 17) * QINV;
            float2 l0 = __half22float2(*(const __half2*)&u0.x);
            float2 h0 = __half22float2(*(const __half2*)&u0.y);
            float2 l1 = __half22float2(*(const __half2*)&u1.x);
            float2 h1v = __half22float2(*(const __half2*)&u1.y);
            float2 l2 = __half22float2(*(const __half2*)&u2.x);
            float2 h2v = __half22float2(*(const __half2*)&u2.y);
            float2 l3 = __half22float2(*(const __half2*)&u3.x);
            float2 h3v = __half22float2(*(const __half2*)&u3.y);
            float2 l4 = __half22float2(*(const __half2*)&u4.x);
            float2 h4v = __half22float2(*(const __half2*)&u4.y);
            float2 l5 = __half22float2(*(const __half2*)&u5.x);
            float2 h5v = __half22float2(*(const __half2*)&u5.y);
            float2 l6 = __half22float2(*(const __half2*)&u6.x);
            float2 h6v = __half22float2(*(const __half2*)&u6.y);
            float2 l7 = __half22float2(*(const __half2*)&u7.x);
            float2 h7v = __half22float2(*(const __half2*)&u7.y);
            a0 += w0 * l0.x + w1 * l1.x + w2 * l2.x + w3 * l3.x
                + w4 * l4.x + w5 * l5.x + w6 * l6.x + w7 * l7.x;
            a1 += w0 * l0.y + w1 * l1.y + w2 * l2.y + w3 * l3.y
                + w4 * l4.y + w5 * l5.y + w6 * l6.y + w7 * l7.y;
            a2 += w0 * h0.x + w1 * h1v.x + w2 * h2v.x + w3 * h3v.x
                + w4 * h4v.x + w5 * h5v.x + w6 * h6v.x + w7 * h7v.x;
            a3 += w0 * h0.y + w1 * h1v.y + w2 * h2v.y + w3 * h3v.y
                + w4 * h4v.y + w5 * h5v.y + w6 * h6v.y + w7 * h7v.y;
            e0 = f0; e1 = f1; e2 = f2; e3 = f3; e4 = f4r; e5 = f5; e6 = f6; e7 = f7;
            f0 = g0; f1 = g1; f2 = g2; f3 = g3; f4r = g4; f5 = g5; f6 = g6; f7 = g7;
            u0 = v0; u1 = v1; u2 = v2; u3 = v3; u4 = v4; u5 = v5; u6 = v6; u7 = v7;
        }
        // epilogue A
        {
            uint2 v0 = hp2[(f0 & 0x1FFFF) * 2 + c2];
            uint2 v1 = hp2[(f1 & 0x1FFFF) * 2 + c2];
            uint2 v2 = hp2[(f2 & 0x1FFFF) * 2 + c2];
            uint2 v3 = hp2[(f3 & 0x1FFFF) * 2 + c2];
            uint2 v4 = hp2[(f4r & 0x1FFFF) * 2 + c2];
            uint2 v5 = hp2[(f5 & 0x1FFFF) * 2 + c2];
            uint2 v6 = hp2[(f6 & 0x1FFFF) * 2 + c2];
            uint2 v7 = hp2[(f7 & 0x1FFFF) * 2 + c2];
            float w0 = (float)(e0 >> 17) * QINV;
            float w1 = (float)(e1 >> 17) * QINV;
            float w2 = (float)(e2 >> 17) * QINV;
            float w3 = (float)(e3 >> 17) * QINV;
            float w4 = (float)(e4 >> 17) * QINV;
            float w5 = (float)(e5 >> 17) * QINV;
            float w6 = (float)(e6 >> 17) * QINV;
            float w7 = (float)(e7 >> 17) * QINV;
            float2 l0 = __half22float2(*(const __half2*)&u0.x);
            float2 h0 = __half22float2(*(const __half2*)&u0.y);
            float2 l1 = __half22float2(*(const __half2*)&u1.x);
            float2 h1v = __half22float2(*(const __half2*)&u1.y);
            float2 l2 = __half22float2(*(const __half2*)&u2.x);
            float2 h2v = __half22float2(*(const __half2*)&u2.y);
            float2 l3 = __half22float2(*(const __half2*)&u3.x);
            float2 h3v = __half22float2(*(const __half2*)&u3.y);
            float2 l4 = __half22float2(*(const __half2*)&u4.x);
            float2 h4v = __half22float2(*(const __half2*)&u4.y);
            float2 l5 = __half22float2(*(const __half2*)&u5.x);
            float2 h5v = __half22float2(*(const __half2*)&u5.y);
            float2 l6 = __half22float2(*(const __half2*)&u6.x);
            float2 h6v = __half22float2(*(const __half2*)&u6.y);
            float2 l7 = __half22float2(*(const __half2*)&u7.x);
            float2 h7v = __half22float2(*(const __half2*)&u7.y);
            a0 += w0 * l0.x + w1 * l1.x + w2 * l2.x + w3 * l3.x
                + w4 * l4.x + w5 * l5.x + w6 * l6.x + w7 * l7.x;
            a1 += w0 * l0.y + w1 * l1.y + w2 * l2.y + w3 * l3.y
                + w4 * l4.y + w5 * l5.y + w6 * l6.y + w7 * l7.y;
            a2 += w0 * h0.x + w1 * h1v.x + w2 * h2v.x + w3 * h3v.x
                + w4 * h4v.x + w5 * h5v.x + w6 * h6v.x + w7 * h7v.x;
            a3 += w0 * h0.y + w1 * h1v.y + w2 * h2v.y + w3 * h3v.y
                + w4 * h4v.y + w5 * h5v.y + w6 * h6v.y + w7 * h7v.y;
            e0 = f0; e1 = f1; e2 = f2; e3 = f3; e4 = f4r; e5 = f5; e6 = f6; e7 = f7;
            u0 = v0; u1 = v1; u2 = v2; u3 = v3; u4 = v4; u5 = v5; u6 = v6; u7 = v7;
            i += 8;
        }
        // epilogue B
        {
            float w0 = (float)(e0 >> 17) * QINV;
            float w1 = (float)(e1 >> 17) * QINV;
            float w2 = (float)(e2 >> 17) * QINV;
            float w3 = (float)(e3 >> 17) * QINV;
            float w4 = (float)(e4 >> 17) * QINV;
            float w5 = (float)(e5 >> 17) * QINV;
            float w6 = (float)(e6 >> 17) * QINV;
            float w7 = (float)(e7 >> 17) * QINV;
            float2 l0 = __half22float2(*(const __half2*)&u0.x);
            float2 h0 = __half22float2(*(const __half2*)&u0.y);
            float2 l1 = __half22float2(*(const __half2*)&u1.x);
            float2 h1v = __half22float2(*(const __half2*)&u1.y);
            float2 l2 = __half22float2(*(const __half2*)&u2.x);
            float2 h2v = __half22float2(*(const __half2*)&u2.y);
            float2 l3 = __half22float2(*(const __half2*)&u3.x);
            float2 h3v = __half22float2(*(const __half2*)&u3.y);
            float2 l4 = __half22float2(*(const __half2*)&u4.x);
            float2 h4v = __half22float2(*(const __half2*)&u4.y);
            float2 l5 = __half22float2(*(const __half2*)&u5.x);
            float2 h5v = __half22float2(*(const __half2*)&u5.y);
            float2 l6 = __half22float2(*(const __half2*)&u6.x);
            float2 h6v = __half22float2(*(const __half2*)&u6.y);
            float2 l7 = __half22float2(*(const __half2*)&u7.x);
            float2 h7v = __half22float2(*(const __half2*)&u7.y);
            a0 += w0 * l0.x + w1 * l1.x + w2 * l2.x + w3 * l3.x
                + w4 * l4.x + w5 * l5.x + w6 * l6.x + w7 * l7.x;
            a1 += w0 * l0.y + w1 * l1.y + w2 * l2.y + w3 * l3.y
                + w4 * l4.y + w5 * l5.y + w6 * l6.y + w7 * l7.y;
            a2 += w0 * h0.x + w1 * h1v.x + w2 * h2v.x + w3 * h3v.x
                + w4 * h4v.x + w5 * h5v.x + w6 * h6v.x + w7 * h7v.x;
            a3 += w0 * h0.y + w1 * h1v.y + w2 * h2v.y + w3 * h3v.y
                + w4 * h4v.y + w5 * h5v.y + w6 * h6v.y + w7 * h7v.y;
            i += 8;
        }
    }
    for (; i + 3 < c; i += 4) {
        unsigned e0 = cbuf[s0 + i];
        unsigned e1 = cbuf[s0 + i + 1];
        unsigned e2 = cbuf[s0 + i + 2];
        unsigned e3 = cbuf[s0 + i + 3];
        uint2 u0 = hp2[(e0 & 0x1FFFF) * 2 + c2];
        uint2 u1 = hp2[(e1 & 0x1FFFF) * 2 + c2];
        uint2 u2 = hp2[(e2 & 0x1FFFF) * 2 + c2];
        uint2 u3 = hp2[(e3 & 0x1FFFF) * 2 + c2];
        float w0 = (float)(e0 >> 17) * QINV;
        float w1 = (float)(e1 >> 17) * QINV;
        float w2 = (float)(e2 >> 17) * QINV;
        float w3 = (float)(e3 >> 17) * QINV;
        float2 l0 = __half22float2(*(const __half2*)&u0.x);
        float2 h0 = __half22float2(*(const __half2*)&u0.y);
        float2 l1 = __half22float2(*(const __half2*)&u1.x);
        float2 h1v = __half22float2(*(const __half2*)&u1.y);
        float2 l2 = __half22float2(*(const __half2*)&u2.x);
        float2 h2v = __half22float2(*(const __half2*)&u2.y);
        float2 l3 = __half22float2(*(const __half2*)&u3.x);
        float2 h3v = __half22float2(*(const __half2*)&u3.y);
        a0 += w0 * l0.x + w1 * l1.x + w2 * l2.x + w3 * l3.x;
        a1 += w0 * l0.y + w1 * l1.y + w2 * l2.y + w3 * l3.y;
        a2 += w0 * h0.x + w1 * h1v.x + w2 * h2v.x + w3 * h3v.x;
        a3 += w0 * h0.y + w1 * h1v.y + w2 * h2v.y + w3 * h3v.y;
    }
    for (; i < c; ++i) {
        unsigned e0 = cbuf[s0 + i];
        uint2 u0 = hp2[(e0 & 0x1FFFF) * 2 + c2];
        float w0 = (float)(e0 >> 17) * QINV;
        float2 l0 = __half22float2(*(const __half2*)&u0.x);
        float2 h0 = __half22float2(*(const __half2*)&u0.y);
        a0 += w0 * l0.x;
        a1 += w0 * l0.y;
        a2 += w0 * h0.x;
        a3 += w0 * h0.y;
    }
    float di = dinv[n];
    int cb = 4 * c2;
    float va0 = di * a0 + b2[cb + 0];
    float va1 = di * a1 + b2[cb + 1];
    float va2 = di * a2 + b2[cb + 2];
    float va3 = (c2 == 0) ? (di * a3 + b2[3]) : -1e30f;
    float m = fmaxf(fmaxf(va0, va1), fmaxf(va2, va3));
    m = fmaxf(m, __shfl_xor(m, 1, 2));
    float s = __expf(va0 - m) + __expf(va1 - m) + __expf(va2 - m) + __expf(va3 - m);
    s += __shfl_xor(s, 1, 2);
    float lse = m + __logf(s);
    int base = n * NC + cb;
    out[base + 0] = va0 - lse;
    out[base + 1] = va1 - lse;
    out[base + 2] = va2 - lse;
    if (c2 == 0) out[base + 3] = va3 - lse;
}

extern "C" void kernel_launch(void* const* d_in, const int* in_sizes, int n_in,
                              void* d_out, int out_size, void* d_ws, size_t ws_size,
                              hipStream_t stream) {
    const float* x  = (const float*)d_in[0];
    const int*   ei = (const int*)d_in[1];
    const float* ew = (const float*)d_in[2];
    const float* W1 = (const float*)d_in[3];
    const float* b1 = (const float*)d_in[4];
    const float* W2 = (const float*)d_in[5];
    const float* b2 = (const float*)d_in[6];
    float* out = (float*)d_out;

    const int* srcp = ei;
    const int* dstp = ei + NE;

    // ws layout (4B units)
    float*  ws   = (float*)d_ws;
    float*  dinv = ws;                          // 100352
    __half* h1p  = (__half*)(ws + 100352);      // NN*16 halves = 800000 units
    __half* h2p  = (__half*)(ws + 900352);      // NN*8 halves = 400000 units
    int*    gcur = (int*)(ws + 1300352);        // 1024
    int*    rs   = (int*)(ws + 1301376);        // 100352
    int*    rc   = (int*)(ws + 1401728);        // 100352
    uint2*  ebuf = (uint2*)(ws + 1502080);      // NB*CAP uint2 = 7,206,912 units
    const unsigned* cbuf = (const unsigned*)ebuf;  // compact u32 overlay after k_sort

    auto cdiv = [](long long a, long long b) { return (int)((a + b - 1) / b); };

    hipMemsetAsync(gcur, 0, NB * sizeof(int), stream);
    k_append<<<AB, 1024, 0, stream>>>(srcp, dstp, ew, gcur, ebuf);
    k_sort<<<NB, 1024, 0, stream>>>(gcur, ebuf, rs, rc, dinv);
    k_proj1<<<cdiv(NN, 64), 256, 0, stream>>>(x, W1, dinv, h1p);  // 1563 blocks, 4 tiles each
    k_agg1p<<<cdiv((long long)NN * 4, 256), 256, 0, stream>>>(rs, rc, cbuf, h1p, dinv, b1, W2, h2p);
    k_agg2_lsm<<<cdiv((long long)NN * 2, 256), 256, 0, stream>>>(rs, rc, cbuf, h2p, dinv, b2, out);
}